// Round 2
// baseline (447.764 us; speedup 1.0000x reference)
//
#include <hip/hip_runtime.h>
#include <math.h>

#define NN    50000
#define NE    1600000
#define INDIM 2000
#define HID   8

// ================= CSR build =================

__global__ __launch_bounds__(256) void k_zero(int* __restrict__ cnt, int n) {
    int i = blockIdx.x * 256 + threadIdx.x;
    if (i < n) cnt[i] = 0;
}

__global__ __launch_bounds__(256) void k_cnt(const int* __restrict__ dst,
                                             int* __restrict__ cnt, int e) {
    int i = blockIdx.x * 256 + threadIdx.x;
    if (i < e) atomicAdd(&cnt[dst[i]], 1);
}

// per-block exclusive scan + block sums
__global__ __launch_bounds__(256) void k_scan_a(const int* __restrict__ cnt,
                                                int* __restrict__ off,
                                                int* __restrict__ bsum, int n) {
    __shared__ int s[256];
    int i = blockIdx.x * 256 + threadIdx.x;
    int v = (i < n) ? cnt[i] : 0;
    s[threadIdx.x] = v;
    __syncthreads();
#pragma unroll
    for (int o = 1; o < 256; o <<= 1) {
        int t = (threadIdx.x >= o) ? s[threadIdx.x - o] : 0;
        __syncthreads();
        s[threadIdx.x] += t;
        __syncthreads();
    }
    int incl = s[threadIdx.x];
    if (i < n) off[i] = incl - v;                 // exclusive within block
    if (threadIdx.x == 255) bsum[blockIdx.x] = incl;
}

// scan the (<=256) block sums in one block
__global__ __launch_bounds__(256) void k_scan_b(int* __restrict__ bsum, int nb) {
    __shared__ int s[256];
    int t = threadIdx.x;
    int v = (t < nb) ? bsum[t] : 0;
    s[t] = v;
    __syncthreads();
#pragma unroll
    for (int o = 1; o < 256; o <<= 1) {
        int x = (t >= o) ? s[t - o] : 0;
        __syncthreads();
        s[t] += x;
        __syncthreads();
    }
    if (t < nb) bsum[t] = s[t] - v;               // exclusive
}

__global__ __launch_bounds__(256) void k_scan_c(int* __restrict__ off,
                                                int* __restrict__ cur,
                                                const int* __restrict__ bsum,
                                                int n, int e) {
    int i = blockIdx.x * 256 + threadIdx.x;
    if (i < n) {
        int o = off[i] + bsum[blockIdx.x];
        off[i] = o;
        cur[i] = o;
    }
    if (i == 0) off[n] = e;
}

// rec[p] = {src, w} at a slot inside dst's bucket
__global__ __launch_bounds__(256) void k_fill(const int* __restrict__ src,
                                              const int* __restrict__ dst,
                                              const float* __restrict__ w,
                                              int* __restrict__ cur,
                                              int2* __restrict__ rec, int e) {
    int i = blockIdx.x * 256 + threadIdx.x;
    if (i < e) {
        int d = dst[i];
        int p = atomicAdd(&cur[d], 1);
        int2 r;
        r.x = src[i];
        r.y = __float_as_int(w[i]);
        rec[p] = r;
    }
}

// per node: deg = 1 + sum(w in bucket); dinv = rsqrt(deg); rec.w *= dinv (in place)
__global__ __launch_bounds__(256) void k_node(const int* __restrict__ off,
                                              int2* __restrict__ rec,
                                              float* __restrict__ dinv, int n) {
    int t = blockIdx.x * 256 + threadIdx.x;
    int i = t >> 3, sl = t & 7;
    if (i >= n) return;
    int lo = off[i], hi = off[i + 1];
    float sum = 0.f;
    for (int p = lo + sl; p < hi; p += 8)
        sum += __int_as_float(rec[p].y);
    sum += __shfl_xor(sum, 1, 8);
    sum += __shfl_xor(sum, 2, 8);
    sum += __shfl_xor(sum, 4, 8);
    float dv = rsqrtf(sum + 1.0f);                // +1 self-loop weight
    if (sl == 0) dinv[i] = dv;
    for (int p = lo + sl; p < hi; p += 8) {
        int2 r = rec[p];
        r.y = __float_as_int(__int_as_float(r.y) * dv);
        rec[p] = r;
    }
}

// ================= layer 1 GEMM: g1 = dinv * (x @ W1) =================
// 8 rows/wave, W1^T in LDS, multiplexed butterfly reduce, contiguous stores.

__global__ __launch_bounds__(256) void k_gemm1(const float* __restrict__ x,
                                               const float* __restrict__ W1,
                                               const float* __restrict__ dinv,
                                               float* __restrict__ g1, int n) {
    __shared__ float Wt[HID][INDIM];              // 64000 B
    for (int idx = threadIdx.x; idx < INDIM * HID; idx += 256) {
        int c = idx >> 3, j = idx & 7;
        Wt[j][c] = W1[idx];
    }
    __syncthreads();

    const int wave = threadIdx.x >> 6;
    const int lane = threadIdx.x & 63;
    const int row0 = (blockIdx.x * 4 + wave) * 8;

    float acc[64];
#pragma unroll
    for (int v = 0; v < 64; ++v) acc[v] = 0.f;

#pragma unroll
    for (int k = 0; k < 8; ++k) {
        const int c = k * 256 + lane * 4;
        if (c < INDIM) {
            float4 wv[HID];
#pragma unroll
            for (int j = 0; j < HID; ++j)
                wv[j] = *(const float4*)&Wt[j][c];
#pragma unroll
            for (int r = 0; r < 8; ++r) {
                const int row = min(row0 + r, n - 1);
                const float4 xv = *(const float4*)&x[(size_t)row * INDIM + c];
#pragma unroll
                for (int j = 0; j < HID; ++j)
                    acc[r * 8 + j] += xv.x * wv[j].x + xv.y * wv[j].y +
                                      xv.z * wv[j].z + xv.w * wv[j].w;
            }
        }
    }

    // multiplexed butterfly: lane l ends owning full sum of value v=l
    // (value index v = r*8+j; bit s of v pairs with lane bit s)
#pragma unroll
    for (int s = 0; s < 6; ++s) {
        const int o = 1 << s;
        const bool hb = (lane & o) != 0;
        const int np = 64 >> (s + 1);
#pragma unroll
        for (int p = 0; p < np; ++p) {
            float v0 = acc[2 * p], v1 = acc[2 * p + 1];
            float send = hb ? v0 : v1;
            float recv = __shfl_xor(send, o);
            acc[p] = (hb ? v1 : v0) + recv;
        }
    }

    const int r = lane >> 3, j = lane & 7;
    const int row = row0 + r;
    if (row < n) g1[(size_t)row * HID + j] = dinv[row] * acc[0];
}

// ================= gather layer 1 (+ bias, relu, @W2 fused) =================
// 8 lanes per node; lane = channel. conv1 = sum + self + b1; t=relu;
// h2 = t @ W2 via 8-lane shuffles; g2 = dinv * h2.

__global__ __launch_bounds__(256) void k_gather1(const int2* __restrict__ rec,
                                                 const int* __restrict__ off,
                                                 const float* __restrict__ dinv,
                                                 const float* __restrict__ g1,
                                                 const float* __restrict__ b1,
                                                 const float* __restrict__ W2,
                                                 float* __restrict__ g2, int n) {
    __shared__ float sW[HID * HID];
    __shared__ float sb[HID];
    if (threadIdx.x < HID * HID) sW[threadIdx.x] = W2[threadIdx.x];
    if (threadIdx.x < HID) sb[threadIdx.x] = b1[threadIdx.x];
    __syncthreads();

    int t = blockIdx.x * 256 + threadIdx.x;
    int i = t >> 3, ch = t & 7;
    if (i >= n) return;

    const int lo = off[i], hi = off[i + 1];
    float acc = 0.f;
    for (int p = lo; p < hi; ++p) {
        const int2 r = rec[p];
        acc = fmaf(__int_as_float(r.y), g1[(size_t)r.x * HID + ch], acc);
    }
    const float di = dinv[i];
    acc = fmaf(di, g1[(size_t)i * HID + ch], acc);   // self-loop

    const float tv = fmaxf(acc + sb[ch], 0.f);       // + b1, relu
    float h = 0.f;
#pragma unroll
    for (int k = 0; k < HID; ++k)
        h = fmaf(__shfl(tv, k, 8), sW[k * HID + ch], h);
    g2[(size_t)i * HID + ch] = di * h;
}

// ================= gather layer 2 (+ bias, log_softmax fused) =================

__global__ __launch_bounds__(256) void k_gather2(const int2* __restrict__ rec,
                                                 const int* __restrict__ off,
                                                 const float* __restrict__ dinv,
                                                 const float* __restrict__ g2,
                                                 const float* __restrict__ b2,
                                                 float* __restrict__ out, int n) {
    __shared__ float sb[HID];
    if (threadIdx.x < HID) sb[threadIdx.x] = b2[threadIdx.x];
    __syncthreads();

    int t = blockIdx.x * 256 + threadIdx.x;
    int i = t >> 3, ch = t & 7;
    if (i >= n) return;

    const int lo = off[i], hi = off[i + 1];
    float acc = 0.f;
    for (int p = lo; p < hi; ++p) {
        const int2 r = rec[p];
        acc = fmaf(__int_as_float(r.y), g2[(size_t)r.x * HID + ch], acc);
    }
    const float di = dinv[i];
    acc = fmaf(di, g2[(size_t)i * HID + ch], acc);   // self-loop
    const float v = acc + sb[ch];

    float m = v;
    m = fmaxf(m, __shfl_xor(m, 1, 8));
    m = fmaxf(m, __shfl_xor(m, 2, 8));
    m = fmaxf(m, __shfl_xor(m, 4, 8));
    float s = expf(v - m);
    s += __shfl_xor(s, 1, 8);
    s += __shfl_xor(s, 2, 8);
    s += __shfl_xor(s, 4, 8);
    out[(size_t)i * HID + ch] = v - (m + logf(s));
}

// ================= launcher =================

extern "C" void kernel_launch(void* const* d_in, const int* in_sizes, int n_in,
                              void* d_out, int out_size, void* d_ws, size_t ws_size,
                              hipStream_t stream) {
    const float* x   = (const float*)d_in[0];
    const int*   src = (const int*)d_in[1];
    const int*   dst = (const int*)d_in[2];
    const float* ew  = (const float*)d_in[3];
    const float* W1  = (const float*)d_in[4];
    const float* b1  = (const float*)d_in[5];
    const float* W2  = (const float*)d_in[6];
    const float* b2  = (const float*)d_in[7];
    float* out = (float*)d_out;

    // workspace layout (8-B aligned first)
    int2*  rec  = (int2*)d_ws;                    // NE
    int*   off  = (int*)(rec + NE);               // NN+1
    int*   cur  = off + NN + 1;                   // NN
    int*   cnt  = cur + NN;                       // NN
    int*   bsum = cnt + NN;                       // 256
    float* dinv = (float*)(bsum + 256);           // NN
    float* g1   = dinv + NN;                      // NN*HID
    float* g2   = g1 + (size_t)NN * HID;          // NN*HID

    const int B = 256;
    const int gN  = (NN + B - 1) / B;             // 196
    const int gE  = (NE + B - 1) / B;             // 6250
    const int gN8 = (NN * HID + B - 1) / B;       // 1563
    const int gG  = (NN + 31) / 32;               // 1563

    k_zero   <<<gN,  B, 0, stream>>>(cnt, NN);
    k_cnt    <<<gE,  B, 0, stream>>>(dst, cnt, NE);
    k_scan_a <<<gN,  B, 0, stream>>>(cnt, off, bsum, NN);
    k_scan_b <<<1,   B, 0, stream>>>(bsum, gN);
    k_scan_c <<<gN,  B, 0, stream>>>(off, cur, bsum, NN, NE);
    k_fill   <<<gE,  B, 0, stream>>>(src, dst, ew, cur, rec, NE);
    k_node   <<<gN8, B, 0, stream>>>(off, rec, dinv, NN);

    k_gemm1  <<<gG,  B, 0, stream>>>(x, W1, dinv, g1, NN);

    k_gather1<<<gN8, B, 0, stream>>>(rec, off, dinv, g1, b1, W2, g2, NN);
    k_gather2<<<gN8, B, 0, stream>>>(rec, off, dinv, g2, b2, out, NN);
}